// Round 6
// baseline (3737.293 us; speedup 1.0000x reference)
//
#include <hip/hip_runtime.h>
#include <stdint.h>

namespace {

constexpr int H = 512, V = 64, B = 8, T = 48, D1 = 49, NDEC = 45, NSTEP = 102;
constexpr int NBLK = 256, TPB = 512;
constexpr int NG = 8, GMEM = NBLK / NG;

// buf layout: [p2][g][slot][b][hl] ; flat = (p2*64+g)*3136 + slot*64 + b*8 + hl
constexpr size_t SZ_BUF  = (size_t)4 * 64 * D1 * B * 8;   // 802816 floats
constexpr size_t OFF_IDX = SZ_BUF;                        // NSTEP*8 ints
constexpr size_t OFF_BAR = OFF_IDX + (size_t)NSTEP * B;   // 512 ints
constexpr size_t P2STRIDE = (size_t)64 * 3136;            // 200704

// relaxed agent-scope (sc1) accessors: coherent at L3 across XCDs, no fences
__device__ __forceinline__ float ldA(const float* p) {
  return __hip_atomic_load(p, __ATOMIC_RELAXED, __HIP_MEMORY_SCOPE_AGENT);
}
__device__ __forceinline__ void stA(float* p, float v) {
  __hip_atomic_store(p, v, __ATOMIC_RELAXED, __HIP_MEMORY_SCOPE_AGENT);
}
__device__ __forceinline__ int ldAi(const int* p) {
  return __hip_atomic_load(p, __ATOMIC_RELAXED, __HIP_MEMORY_SCOPE_AGENT);
}
__device__ __forceinline__ void stAi(int* p, int v) {
  __hip_atomic_store(p, v, __ATOMIC_RELAXED, __HIP_MEMORY_SCOPE_AGENT);
}

__device__ __forceinline__ void tf2x32(uint32_t k0, uint32_t k1,
                                       uint32_t& x0, uint32_t& x1) {
  const uint32_t ks2 = k0 ^ k1 ^ 0x1BD11BDAu;
  x0 += k0; x1 += k1;
#define RR(r) { x0 += x1; x1 = (x1 << (r)) | (x1 >> (32-(r))); x1 ^= x0; }
  RR(13) RR(15) RR(26) RR(6)  x0 += k1;  x1 += ks2 + 1u;
  RR(17) RR(29) RR(16) RR(24) x0 += ks2; x1 += k0 + 2u;
  RR(13) RR(15) RR(26) RR(6)  x0 += k0;  x1 += k1 + 3u;
  RR(17) RR(29) RR(16) RR(24) x0 += k1;  x1 += ks2 + 4u;
  RR(13) RR(15) RR(26) RR(6)  x0 += ks2; x1 += k0 + 5u;
#undef RR
}

__device__ __forceinline__ float gumbel_from_bits(uint32_t bits) {
  float u = __uint_as_float((bits >> 9) | 0x3F800000u) - 1.0f;
  u = u + 1e-9f;
  return -logf(-logf(u));
}

__global__ __launch_bounds__(512) void k_zero(float* __restrict__ ws) {
  int* bar = (int*)ws + OFF_BAR;
  stAi(&bar[threadIdx.x], 0);
}

// fence-free two-level grid barrier. All shared data uses sc1 accesses, so
// visibility needs only store-completion (vmcnt) before the arrive RMW.
__device__ __forceinline__ void gbar(int* bar, int grp, int ep) {
  asm volatile("s_waitcnt vmcnt(0)" ::: "memory");  // every wave drains stores
  __syncthreads();
  if (threadIdx.x == 0) {
    int old = __hip_atomic_fetch_add(&bar[16 + 16 * grp], 1,
                                     __ATOMIC_RELAXED, __HIP_MEMORY_SCOPE_AGENT);
    if (((old + 1) & (GMEM - 1)) == 0) {                 // group closer
      int oldG = __hip_atomic_fetch_add(&bar[0], 1,
                                        __ATOMIC_RELAXED, __HIP_MEMORY_SCOPE_AGENT);
      if (((oldG + 1) & (NG - 1)) == 0) {                // global closer
        #pragma unroll
        for (int q = 0; q < NG; ++q)
          stAi(&bar[160 + 16 * q], ep);
      }
    }
    int guard = 0;
    while (ldAi(&bar[160 + 16 * grp]) < ep) {
      __builtin_amdgcn_s_sleep(2);
      if (++guard > (1 << 20)) break;   // fail-visible, never hangs
    }
  }
  __syncthreads();
}

__global__ __launch_bounds__(TPB, 2) void k_main(
    const float* __restrict__ x,  const float* __restrict__ wa,
    const float* __restrict__ ba, const float* __restrict__ lat,
    const float* __restrict__ tau,const float* __restrict__ we,
    const float* __restrict__ be, float* __restrict__ ws,
    float* __restrict__ out) {
  const int blk = blockIdx.x, tid = threadIdx.x;
  const int w = tid >> 6, lane = tid & 63;
  const int p = blk >> 6, g = blk & 63, grp = blk & 7;
  float* buf = ws;
  int* idxA = (int*)ws + OFF_IDX;
  int* bar  = (int*)ws + OFF_BAR;

  __shared__ float s_tc[8 * 128];    // pre-clipped tau slice
  __shared__ float s_lat[8 * 128];
  __shared__ float s_waT[64 * 128];  // TRANSPOSED: s_waT[v*128+il] (32 KB)
  __shared__ float s_h[8 * 128];     // h[b][il] slice for scat
  __shared__ float s_hdl[512];       // leader: full h_del of its sample
  __shared__ float s_red[256];       // leader: y partials
  __shared__ int   s_ptr[8], s_cidx[8], s_done8[8];

  // ---------------- init ----------------
  for (size_t i = (size_t)(blk * TPB + tid); i < SZ_BUF; i += (size_t)NBLK * TPB)
    stA(&buf[i], 0.0f);
  for (int q = tid; q < 64 * 128; q += TPB) {
    int v = q >> 7, il = q & 127;
    s_waT[q] = wa[(size_t)(p * 128 + il) * V + v];
  }
  for (int q = tid; q < 8 * 128; q += TPB) {
    int ww = q >> 7, il = q & 127;
    int ho = g * 8 + ww, i = p * 128 + il;
    float tv = tau[(size_t)ho * H + i];
    s_tc[q]  = fminf(fmaxf(tv, 1.0f), 48.0f);
    s_lat[q] = lat[(size_t)ho * H + i];
  }
  if (tid < 8) { s_ptr[tid] = 0; s_cidx[tid] = 0; s_done8[tid] = 0; }
  uint32_t ka = 0u, kb = (uint32_t)blk;
  if (blk < B) tf2x32(0u, 42u, ka, kb);     // leader sample key

  gbar(bar, grp, 1);

  // ---------------- 102 sequential steps ----------------
  for (int t = 0; t < NSTEP; ++t) {
    const bool thinkM = (t >= T && t < T + 9);
    const bool decM   = (t >= T + 9);

    // replicated control-state update (thread b handles sample b)
    if (tid < 8 && t >= 1) {
      const int b = tid;
      const bool prevThink = (t - 1 >= T) && (t - 1 < T + 9);
      const bool aP = prevThink ? (s_done8[b] == 0) : true;
      if (t - 1 >= T) {
        int ix = ldAi(&idxA[(t - 1) * 8 + b]);
        if (aP) s_cidx[b] = ix;
        if (prevThink && (ix == 63 || (t - 1 - T) == 8)) s_done8[b] = 1;
      }
      if (aP) { int pv = s_ptr[b]; s_ptr[b] = (pv + 1 == D1) ? 0 : pv + 1; }
    }
    __syncthreads();

    int actM = 0;
    #pragma unroll
    for (int b = 0; b < B; ++b)
      actM |= ((thinkM ? (s_done8[b] ^ 1) : 1) & 1) << b;

    // control: h-slice for this block's input chunk
    #pragma unroll
    for (int it2 = 0; it2 < 2; ++it2) {
      int q = tid + it2 * TPB;
      int b = q >> 7, il = q & 127;
      int j = p * 128 + il;
      size_t base = (size_t)(j >> 3) * 3136 + (size_t)s_ptr[b] * 64 + b * 8 + (j & 7);
      float h0 = ldA(&buf[base]);
      float h1 = ldA(&buf[base + P2STRIDE]);
      float h2 = ldA(&buf[base + 2 * P2STRIDE]);
      float h3 = ldA(&buf[base + 3 * P2STRIDE]);
      float hd = ((h0 + h1) + h2) + h3;
      float acc;
      if (t <= T) {      // encoder rows; first think step uses x[:,T-1,:]
        const float* xr = x + ((size_t)b * T + (t < T ? t : T - 1)) * V;
        acc = ba[j] + hd;
        #pragma unroll
        for (int v = 0; v < V; v += 4) {
          float4 x4 = *(const float4*)(xr + v);
          float w0 = s_waT[(v + 0) * 128 + il];
          float w1 = s_waT[(v + 1) * 128 + il];
          float w2 = s_waT[(v + 2) * 128 + il];
          float w3 = s_waT[(v + 3) * 128 + il];
          acc = fmaf(w0, x4.x, acc); acc = fmaf(w1, x4.y, acc);
          acc = fmaf(w2, x4.z, acc); acc = fmaf(w3, x4.w, acc);
        }
      } else {           // cur is exactly one-hot -> single add (bit-equal)
        acc = (ba[j] + hd) + s_waT[s_cidx[b] * 128 + il];
      }
      s_h[b * 128 + il] = tanhf(acc);
    }
    if (blk < B && t >= T) {   // leader: full h_del of own sample
      int j = tid;
      size_t base = (size_t)(j >> 3) * 3136 + (size_t)s_ptr[blk] * 64 + blk * 8 + (j & 7);
      float h0 = ldA(&buf[base]);
      float h1 = ldA(&buf[base + P2STRIDE]);
      float h2 = ldA(&buf[base + 2 * P2STRIDE]);
      float h3 = ldA(&buf[base + 3 * P2STRIDE]);
      s_hdl[j] = ((h0 + h1) + h2) + h3;
    }
    __syncthreads();

    // leader: y, out, gumbel argmax, idx store
    if (blk < B && t >= T) {
      if (tid < 256) {
        int o = tid >> 2, q2 = tid & 3;
        const float* wer = we + (size_t)o * H + q2 * 128;
        const float* hp  = &s_hdl[q2 * 128];
        float a2 = 0.0f;
        for (int i2 = 0; i2 < 128; i2 += 4) {
          float4 w4 = *(const float4*)(wer + i2);
          a2 = fmaf(w4.x, hp[i2],     a2); a2 = fmaf(w4.y, hp[i2 + 1], a2);
          a2 = fmaf(w4.z, hp[i2 + 2], a2); a2 = fmaf(w4.w, hp[i2 + 3], a2);
        }
        s_red[tid] = a2;
      }
      __syncthreads();
      if (tid < V) {
        const int o = tid, it = t - T;
        float y = ((s_red[o*4] + s_red[o*4+1]) + (s_red[o*4+2] + s_red[o*4+3])) + be[o];
        if (decM && o < V - 1)
          out[((size_t)blk * NDEC + (t - T - 9)) * (V - 1) + o] = y;
        uint32_t data = (it < 9) ? (uint32_t)it : (uint32_t)(10000 + (it - 9));
        uint32_t e = 0u, f = data; tf2x32(ka, kb, e, f);
        uint32_t r0 = 0u, r1 = (uint32_t)o; tf2x32(e, f, r0, r1);
        float bv = y + gumbel_from_bits(r0 ^ r1);
        int bi = o;
        #pragma unroll
        for (int m = 32; m >= 1; m >>= 1) {
          float ov = __shfl_xor(bv, m, 64);
          int   oi = __shfl_xor(bi, m, 64);
          if (ov > bv || (ov == bv && oi < bi)) { bv = ov; bi = oi; }
        }
        if (o == 0) stAi(&idxA[t * 8 + blk], bi);
      }
    } else if (blk < B) {
      __syncthreads();   // keep leader/non-leader barrier counts aligned
    }

    // scat: wave w owns output row ho=g*8+w, lane = delay d
    {
      const float dd = (float)lane;
      const float inv = 1.0f / 24.0f, inv2 = inv * inv;
      float acc[B];
      #pragma unroll
      for (int b = 0; b < B; ++b) acc[b] = 0.0f;
      const float* tcr = &s_tc[w * 128];
      const float* ltr = &s_lat[w * 128];
      for (int ii = 0; ii < 128; ii += 4) {
        float4 t4 = *(const float4*)(tcr + ii);
        float4 l4 = *(const float4*)(ltr + ii);
        float4 h4[B];
        #pragma unroll
        for (int b = 0; b < B; ++b) h4[b] = *(const float4*)(&s_h[b * 128 + ii]);
        const float* tp = (const float*)&t4;
        const float* lp = (const float*)&l4;
        #pragma unroll
        for (int k = 0; k < 4; ++k) {
          float tc = tp[k];
          float cr = fmaxf(0.0f, inv - fabsf((dd - tc) * inv2));
          float q2 = cr * lp[k];
          #pragma unroll
          for (int b = 0; b < B; ++b)
            acc[b] = fmaf(q2, ((const float*)&h4[b])[k], acc[b]);
        }
      }
      if (lane >= 1 && lane <= 48) {
        const size_t cbase = (size_t)(p * 64 + g) * 3136 + w;
        #pragma unroll
        for (int b = 0; b < B; ++b) {
          if ((actM >> b) & 1) {
            int slot = s_ptr[b] + lane; if (slot >= D1) slot -= D1;
            size_t a = cbase + (size_t)slot * 64 + b * 8;
            // d=48 is the FIRST contribution to a freshly-consumed slot:
            // overwrite implements the reference's slot-clear (deferred).
            float old = (lane == 48) ? 0.0f : ldA(&buf[a]);
            stA(&buf[a], old + acc[b]);
          }
        }
      }
    }

    gbar(bar, grp, t + 2);
  }
}

} // anonymous namespace

extern "C" void kernel_launch(void* const* d_in, const int* in_sizes, int n_in,
                              void* d_out, int out_size, void* d_ws, size_t ws_size,
                              hipStream_t stream) {
  (void)in_sizes; (void)n_in; (void)out_size; (void)ws_size;
  const float* x   = (const float*)d_in[0];
  const float* wa  = (const float*)d_in[1];
  const float* ba  = (const float*)d_in[2];
  const float* lat = (const float*)d_in[3];
  const float* tau = (const float*)d_in[4];
  const float* we  = (const float*)d_in[5];
  const float* be  = (const float*)d_in[6];
  float* out = (float*)d_out;
  float* ws  = (float*)d_ws;

  k_zero<<<dim3(1), dim3(512), 0, stream>>>(ws);
  k_main<<<dim3(NBLK), dim3(TPB), 0, stream>>>(x, wa, ba, lat, tau, we, be, ws, out);
}

// Round 7
// 2121.473 us; speedup vs baseline: 1.7617x; 1.7617x over previous
//
#include <hip/hip_runtime.h>
#include <stdint.h>

namespace {

constexpr int H = 512, V = 64, B = 8, T = 48, D1 = 49, NDEC = 45, NSTEP = 102;
constexpr int NBLK = 256, TPB = 512;
constexpr int NG = 8, GMEM = NBLK / NG;

// pub layout: [par][j][b][p2] flat = par*16384 + j*32 + b*4 + p2  (floats)
constexpr size_t OFF_PUB = 0;
constexpr size_t OFF_IDX = 2 * 16384;               // ints from here
constexpr size_t OFF_BAR = OFF_IDX + NSTEP * B;     // 512 ints

// relaxed agent-scope (sc1) accessors: coherent at L3, no fences, no L2 flush
__device__ __forceinline__ float ldA(const float* p) {
  return __hip_atomic_load(p, __ATOMIC_RELAXED, __HIP_MEMORY_SCOPE_AGENT);
}
__device__ __forceinline__ void stA(float* p, float v) {
  __hip_atomic_store(p, v, __ATOMIC_RELAXED, __HIP_MEMORY_SCOPE_AGENT);
}
__device__ __forceinline__ int ldAi(const int* p) {
  return __hip_atomic_load(p, __ATOMIC_RELAXED, __HIP_MEMORY_SCOPE_AGENT);
}
__device__ __forceinline__ void stAi(int* p, int v) {
  __hip_atomic_store(p, v, __ATOMIC_RELAXED, __HIP_MEMORY_SCOPE_AGENT);
}

__device__ __forceinline__ void tf2x32(uint32_t k0, uint32_t k1,
                                       uint32_t& x0, uint32_t& x1) {
  const uint32_t ks2 = k0 ^ k1 ^ 0x1BD11BDAu;
  x0 += k0; x1 += k1;
#define RR(r) { x0 += x1; x1 = (x1 << (r)) | (x1 >> (32-(r))); x1 ^= x0; }
  RR(13) RR(15) RR(26) RR(6)  x0 += k1;  x1 += ks2 + 1u;
  RR(17) RR(29) RR(16) RR(24) x0 += ks2; x1 += k0 + 2u;
  RR(13) RR(15) RR(26) RR(6)  x0 += k0;  x1 += k1 + 3u;
  RR(17) RR(29) RR(16) RR(24) x0 += k1;  x1 += ks2 + 4u;
  RR(13) RR(15) RR(26) RR(6)  x0 += ks2; x1 += k0 + 5u;
#undef RR
}

__device__ __forceinline__ float gumbel_from_bits(uint32_t bits) {
  float u = __uint_as_float((bits >> 9) | 0x3F800000u) - 1.0f;
  u = u + 1e-9f;
  return -logf(-logf(u));
}

__global__ __launch_bounds__(512) void k_zero(float* __restrict__ ws) {
  // zero barrier words + pub parity-0 (read at t=0)
  int* bar = (int*)ws + OFF_BAR;
  if (threadIdx.x < 512) stAi(&bar[threadIdx.x], 0);
  for (int i = threadIdx.x; i < 16384; i += 512) stA(&ws[i], 0.0f);
}

// fence-free two-level grid barrier (r6-proven correct/cheap):
// sc1 data + vmcnt drain before arrive => visibility without cache flushes
__device__ __forceinline__ void gbar(int* bar, int grp, int ep) {
  asm volatile("s_waitcnt vmcnt(0)" ::: "memory");
  __syncthreads();
  if (threadIdx.x == 0) {
    int old = __hip_atomic_fetch_add(&bar[16 + 16 * grp], 1,
                                     __ATOMIC_RELAXED, __HIP_MEMORY_SCOPE_AGENT);
    if (((old + 1) & (GMEM - 1)) == 0) {
      int oldG = __hip_atomic_fetch_add(&bar[0], 1,
                                        __ATOMIC_RELAXED, __HIP_MEMORY_SCOPE_AGENT);
      if (((oldG + 1) & (NG - 1)) == 0) {
        #pragma unroll
        for (int q = 0; q < NG; ++q) stAi(&bar[160 + 16 * q], ep);
      }
    }
    int guard = 0;
    while (ldAi(&bar[160 + 16 * grp]) < ep) {
      __builtin_amdgcn_s_sleep(2);
      if (++guard > (1 << 20)) break;   // fail-visible, never hangs
    }
  }
  __syncthreads();
}

__global__ __launch_bounds__(TPB, 2) void k_main(
    const float* __restrict__ x,  const float* __restrict__ wa,
    const float* __restrict__ ba, const float* __restrict__ lat,
    const float* __restrict__ tau,const float* __restrict__ we,
    const float* __restrict__ be, float* __restrict__ ws,
    float* __restrict__ out) {
  const int blk = blockIdx.x, tid = threadIdx.x;
  const int w = tid >> 6, lane = tid & 63;
  const int p = blk >> 6, g = blk & 63, grp = blk & 7;
  float* pub = ws + OFF_PUB;
  int* idxA = (int*)ws + OFF_IDX;
  int* bar  = (int*)ws + OFF_BAR;

  __shared__ float s_tc[8 * 128];        // pre-clipped tau slice (4 KB)
  __shared__ float s_lat[8 * 128];       // (4 KB)
  __shared__ float s_pub[128 * 35 + 8];  // staged pub chunk, stride-35 pad (~18 KB)
  __shared__ float s_h[8 * 128];         // h[b][il] (4 KB)
  __shared__ float s_buf[8 * 8 * 49];    // DELAY PARTIALS, block-local! (12.5 KB)
  __shared__ float s_hdl[512];           // leader: full h_del (2 KB)
  __shared__ float s_red[256];           // leader: y partials (1 KB)
  __shared__ int   s_ptr[8], s_cidx[8], s_done8[8];

  // ---------------- init ----------------
  for (int q = tid; q < 8 * 8 * 49; q += TPB) s_buf[q] = 0.0f;
  for (int q = tid; q < 8 * 128; q += TPB) {
    int ww = q >> 7, il = q & 127;
    int ho = g * 8 + ww, i = p * 128 + il;
    float tv = tau[(size_t)ho * H + i];
    s_tc[q]  = fminf(fmaxf(tv, 1.0f), 48.0f);
    s_lat[q] = lat[(size_t)ho * H + i];
  }
  if (tid < 8) { s_ptr[tid] = 0; s_cidx[tid] = 0; s_done8[tid] = 0; }
  uint32_t ka = 0u, kb = (uint32_t)blk;
  if (blk < B) tf2x32(0u, 42u, ka, kb);     // leader sample key

  gbar(bar, grp, 1);

  // ---------------- 102 sequential steps ----------------
  for (int t = 0; t < NSTEP; ++t) {
    const bool thinkM = (t >= T && t < T + 9);
    const bool decM   = (t >= T + 9);

    // 1. replicated control-state update (thread b handles sample b)
    if (tid < 8 && t >= 1) {
      const int b = tid;
      const bool prevThink = (t - 1 >= T) && (t - 1 < T + 9);
      const bool aP = prevThink ? (s_done8[b] == 0) : true;
      if (t - 1 >= T) {
        int ix = ldAi(&idxA[(t - 1) * 8 + b]);
        if (aP) s_cidx[b] = ix;
        if (prevThink && (ix == 63 || (t - 1 - T) == 8)) s_done8[b] = 1;
      }
      if (aP) { int pv = s_ptr[b]; s_ptr[b] = (pv + 1 == D1) ? 0 : pv + 1; }
    }
    __syncthreads();

    int actM = 0;
    #pragma unroll
    for (int b = 0; b < B; ++b)
      actM |= ((thinkM ? (s_done8[b] ^ 1) : 1) & 1) << b;

    // 2. stage pub chunk (coalesced); leaders stage full h_del (strided)
    {
      const float* pubR = pub + ((size_t)(t & 1) * 16384 + p * 4096);
      #pragma unroll
      for (int k = 0; k < 8; ++k) {
        int f = k * 512 + tid;
        float v = ldA(&pubR[f]);
        s_pub[(f >> 5) * 35 + (f & 31)] = v;
      }
    }
    if (blk < B && t >= T) {
      const float* pr = pub + ((size_t)(t & 1) * 16384 + tid * 32 + blk * 4);
      float h0 = ldA(pr), h1 = ldA(pr + 1), h2 = ldA(pr + 2), h3 = ldA(pr + 3);
      s_hdl[tid] = ((h0 + h1) + h2) + h3;
    }
    __syncthreads();

    // 3. h for this block's chunk; leaders also y partials
    #pragma unroll
    for (int it2 = 0; it2 < 2; ++it2) {
      int q = tid + it2 * TPB;
      int b = q >> 7, il = q & 127;
      int j = p * 128 + il;
      int sp = il * 35 + b * 4;
      float h0 = s_pub[sp], h1 = s_pub[sp + 1], h2 = s_pub[sp + 2], h3 = s_pub[sp + 3];
      float hd = ((h0 + h1) + h2) + h3;
      float acc;
      if (t <= T) {      // encoder rows; first think step uses x[:,T-1,:]
        const float* xr = x + ((size_t)b * T + (t < T ? t : T - 1)) * V;
        const float* war = wa + (size_t)j * V;
        acc = ba[j] + hd;
        #pragma unroll
        for (int v = 0; v < V; v += 4) {
          float4 w4 = *(const float4*)(war + v);
          float4 x4 = *(const float4*)(xr + v);
          acc = fmaf(w4.x, x4.x, acc); acc = fmaf(w4.y, x4.y, acc);
          acc = fmaf(w4.z, x4.z, acc); acc = fmaf(w4.w, x4.w, acc);
        }
      } else {           // cur is exactly one-hot -> single add (bit-equal)
        acc = (ba[j] + hd) + wa[(size_t)j * V + s_cidx[b]];
      }
      s_h[b * 128 + il] = tanhf(acc);
    }
    if (blk < B && t >= T && tid < 256) {
      int o = tid >> 2, q2 = tid & 3;
      const float* wer = we + (size_t)o * H + q2 * 128;
      const float* hp  = &s_hdl[q2 * 128];
      float a2 = 0.0f;
      for (int i2 = 0; i2 < 128; i2 += 4) {
        float4 w4 = *(const float4*)(wer + i2);
        a2 = fmaf(w4.x, hp[i2],     a2); a2 = fmaf(w4.y, hp[i2 + 1], a2);
        a2 = fmaf(w4.z, hp[i2 + 2], a2); a2 = fmaf(w4.w, hp[i2 + 3], a2);
      }
      s_red[tid] = a2;
    }
    __syncthreads();

    // 4. leaders finalize y/gumbel/idx; everyone scatters into LDS s_buf
    if (blk < B && t >= T && tid < V) {
      const int o = tid, it = t - T;
      float y = ((s_red[o*4] + s_red[o*4+1]) + (s_red[o*4+2] + s_red[o*4+3])) + be[o];
      if (decM && o < V - 1)
        out[((size_t)blk * NDEC + (t - T - 9)) * (V - 1) + o] = y;
      uint32_t data = (it < 9) ? (uint32_t)it : (uint32_t)(10000 + (it - 9));
      uint32_t e = 0u, f = data; tf2x32(ka, kb, e, f);
      uint32_t r0 = 0u, r1 = (uint32_t)o; tf2x32(e, f, r0, r1);
      float bv = y + gumbel_from_bits(r0 ^ r1);
      int bi = o;
      #pragma unroll
      for (int m = 32; m >= 1; m >>= 1) {
        float ov = __shfl_xor(bv, m, 64);
        int   oi = __shfl_xor(bi, m, 64);
        if (ov > bv || (ov == bv && oi < bi)) { bv = ov; bi = oi; }
      }
      if (o == 0) stAi(&idxA[t * 8 + blk], bi);
    }
    {
      const float dd = (float)lane;
      const float inv = 1.0f / 24.0f, inv2 = inv * inv;
      float acc[B];
      #pragma unroll
      for (int b = 0; b < B; ++b) acc[b] = 0.0f;
      const float* tcr = &s_tc[w * 128];
      const float* ltr = &s_lat[w * 128];
      for (int ii = 0; ii < 128; ii += 4) {
        float4 t4 = *(const float4*)(tcr + ii);
        float4 l4 = *(const float4*)(ltr + ii);
        float4 h4[B];
        #pragma unroll
        for (int b = 0; b < B; ++b) h4[b] = *(const float4*)(&s_h[b * 128 + ii]);
        const float* tp = (const float*)&t4;
        const float* lp = (const float*)&l4;
        #pragma unroll
        for (int k = 0; k < 4; ++k) {
          float tc = tp[k];
          float cr = fmaxf(0.0f, inv - fabsf((dd - tc) * inv2));
          float q2 = cr * lp[k];
          #pragma unroll
          for (int b = 0; b < B; ++b)
            acc[b] = fmaf(q2, ((const float*)&h4[b])[k], acc[b]);
        }
      }
      if (lane >= 1 && lane <= 48) {
        #pragma unroll
        for (int b = 0; b < B; ++b) {
          if ((actM >> b) & 1) {
            int slot = s_ptr[b] + lane; if (slot >= D1) slot -= D1;
            int a = (b * 8 + w) * 49 + slot;
            // d=48 is the FIRST write to a freshly-consumed slot: overwrite
            // implements the reference's slot-clear (deferred, r5/r6-proven).
            float old = s_buf[a];
            s_buf[a] = (lane == 48) ? acc[b] : (old + acc[b]);
          }
        }
      }
    }
    __syncthreads();

    // 5. publish next step's h_del partials (ptr_{t+1} known NOW: it only
    //    depends on active_t, not on this step's argmax)
    if (tid < 64) {
      int hl = tid >> 3, b = tid & 7;
      int sn = ((actM >> b) & 1) ? s_ptr[b] + 1 : s_ptr[b];
      if (sn >= D1) sn -= D1;
      float val = s_buf[(b * 8 + hl) * 49 + sn];
      stA(&pub[(size_t)((t + 1) & 1) * 16384 + (g * 8 + hl) * 32 + b * 4 + p], val);
    }

    gbar(bar, grp, t + 2);
  }
}

} // anonymous namespace

extern "C" void kernel_launch(void* const* d_in, const int* in_sizes, int n_in,
                              void* d_out, int out_size, void* d_ws, size_t ws_size,
                              hipStream_t stream) {
  (void)in_sizes; (void)n_in; (void)out_size; (void)ws_size;
  const float* x   = (const float*)d_in[0];
  const float* wa  = (const float*)d_in[1];
  const float* ba  = (const float*)d_in[2];
  const float* lat = (const float*)d_in[3];
  const float* tau = (const float*)d_in[4];
  const float* we  = (const float*)d_in[5];
  const float* be  = (const float*)d_in[6];
  float* out = (float*)d_out;
  float* ws  = (float*)d_ws;

  k_zero<<<dim3(1), dim3(512), 0, stream>>>(ws);
  k_main<<<dim3(NBLK), dim3(TPB), 0, stream>>>(x, wa, ba, lat, tau, we, be, ws, out);
}